// Round 5
// baseline (1119.935 us; speedup 1.0000x reference)
//
#include <hip/hip_runtime.h>
#include <stdint.h>

typedef unsigned int u32;
typedef unsigned long long u64;
typedef __attribute__((ext_vector_type(2))) unsigned long long u64x2;

#define BIMG 8
#define NPROP 4000
#define NCLS 91
#define CM1 90
#define MCAND (NPROP * CM1)      // 360000 candidates per image
#define KPRE 2048
#define NBUCKET 4096
#define NREP 8                   // counter replicas (contention /8)
#define SELCAP 16384
#define NSLOT 32                 // per-row candidate slots (provable max 19)
#define DETS 100
#define WLCAP 2048               // worklist capacity per image
#define SCORE_T 0.05f
#define NMS_T 0.5f
#define BBOX_CLIP 4.135166556742356f   // log(1000/16)

// ---------------- workspace layout (r15: last-block-per-image fused tails) ---
// histrep: [img][rep][bucket]; startrep: [img][bucket][rep]; bcntrep: [rep][img][bucket]
// meta page (4KB, zeroed): meta[0..63] per-image meta; tickets at u32 index
// 128+img*32 (K1), 384+img*32 (K4), 640+img*32 (K6) — 128B apart each.
#define HISTREP_OFF ((size_t)0)                                   // u32[8][8][4096]
#define BCNTREP_OFF (HISTREP_OFF + (size_t)NREP * BIMG * NBUCKET * 4)
#define META_OFF    (BCNTREP_OFF + (size_t)NREP * BIMG * NBUCKET * 4)  // u32[1024]
#define ZERO_BYTES  (META_OFF + 4096)
#define START_OFF   (ZERO_BYTES)                                  // u32[8][4096]
#define HISTTOT_OFF (START_OFF + (size_t)BIMG * NBUCKET * 4)      // u32[8][4096]
#define STARTREP_OFF (HISTTOT_OFF + (size_t)BIMG * NBUCKET * 4)   // u32[8][4096][8]
#define SEL_OFF     (STARTREP_OFF + (size_t)NREP * BIMG * NBUCKET * 4) // u64[8][SELCAP]
#define TBOX_OFF    (SEL_OFF + (size_t)BIMG * SELCAP * 8)         // f32[8][2048][4]
#define TSB_OFF     (TBOX_OFF + (size_t)BIMG * KPRE * 16)         // f32[8][2048][4]
#define TSC_OFF     (TSB_OFF + (size_t)BIMG * KPRE * 16)          // f32[8][2048]
#define TLB_OFF     (TSC_OFF + (size_t)BIMG * KPRE * 4)           // i32[8][2048]
#define TVLB_OFF    (TLB_OFF + (size_t)BIMG * KPRE * 4)           // u64[8][32]
#define WLIST_OFF   (TVLB_OFF + (size_t)BIMG * 32 * 8)            // u32[8][WLCAP]
#define CLIST_OFF   (WLIST_OFF + (size_t)BIMG * WLCAP * 4)        // u64[32000][NSLOT]
#define CVALID_OFF  (CLIST_OFF + (size_t)BIMG * NPROP * NSLOT * 8) // u64[32000][2]
#define MASK_OFF    (CVALID_OFF + (size_t)BIMG * NPROP * 2 * 8)   // u64[8][2048][32]
#define WS_NEED     (MASK_OFF + (size_t)BIMG * KPRE * 32 * 8)     // ~17.3 MB

__device__ __forceinline__ void decode_clip(const float4 rg, const float w, const float h,
                                            const float cx, const float cy,
                                            const float fw, const float fh, float bx[4]) {
    float dx = rg.x / 10.0f;
    float dy = rg.y / 10.0f;
    float dw = fminf(rg.z / 5.0f, BBOX_CLIP);
    float dh = fminf(rg.w / 5.0f, BBOX_CLIP);
    float pcx = dx * w + cx;
    float pcy = dy * h + cy;
    float pw  = expf(dw) * w;
    float phh = expf(dh) * h;
    bx[0] = fminf(fmaxf(pcx - 0.5f * pw,  0.0f), fw);
    bx[1] = fminf(fmaxf(pcy - 0.5f * phh, 0.0f), fh);
    bx[2] = fminf(fmaxf(pcx + 0.5f * pw,  0.0f), fw);
    bx[3] = fminf(fmaxf(pcy + 0.5f * phh, 0.0f), fh);
}

// K1 (fused): r13 k1 body; then last-block-per-image tail runs k2 scan +
// k3 compact for its image. Decoupled-tail pattern: threadfence + one
// ticket atomicAdd per block (release), last ticket => all image blocks'
// writes visible after acquire fence. No dispatch-order/co-residency
// assumption; no spin. Ticket counters 128B apart (r11 contention lesson).
__global__ __launch_bounds__(256) void k1_fused(
    const float* __restrict__ logits, const float* __restrict__ reg,
    const float* __restrict__ props, const int* __restrict__ imh, const int* __restrict__ imw,
    u32* __restrict__ histrep, u64* __restrict__ clist, u64* __restrict__ cvalid,
    u32* __restrict__ histtot, u32* __restrict__ start, u32* __restrict__ startrep,
    u32* __restrict__ meta, u32* __restrict__ wlist,
    u32* __restrict__ bcntrep, u64* __restrict__ sel) {
    __shared__ u32 wsum[4], qws[4];
    __shared__ u32 TbkS, Vs, tick;
    // ---------------- k1 body (r13 verbatim; grid exact so no early return) --
    {
        const int lane = threadIdx.x & 63;
        const int pid = blockIdx.x * 4 + (threadIdx.x >> 6);   // < 32000 always
        const int img = pid / NPROP;
        const float fw = (float)imw[0], fh = (float)imh[0];
        const float* lrow = logits + (size_t)pid * NCLS;
        float v0 = lrow[lane];
        float v1 = (lane < 27) ? lrow[lane + 64] : -3.0e38f;
        float mx = fmaxf(v0, v1);
#pragma unroll
        for (int o = 32; o > 0; o >>= 1) mx = fmaxf(mx, __shfl_xor(mx, o));
        float es = expf(v0 - mx) + ((lane < 27) ? expf(v1 - mx) : 0.0f);
#pragma unroll
        for (int o = 32; o > 0; o >>= 1) es += __shfl_xor(es, o);
        const float thr = mx + logf(es) - 2.9967323f;   // ln(0.05) - 1e-3 margin
        float4 p = reinterpret_cast<const float4*>(props)[pid];
        const float w = p.z - p.x, h = p.w - p.y;
        const float cx = p.x + 0.5f * w, cy = p.y + 0.5f * h;
        const float4* rrow = reinterpret_cast<const float4*>(reg) + (size_t)pid * NCLS;
        const int n = pid - img * NPROP;
        const int rep = n & (NREP - 1);
        const float sh0 = __shfl(v0, (lane + 1) & 63);
        const float sh1 = __shfl(v1, (lane + 1) & 63);
        u64 w0 = 0ull, w1 = 0ull;
        u32 base1 = 0;
#pragma unroll
        for (int batch = 0; batch < 2; ++batch) {
            const int ci = lane + batch * 64;
            bool valid = false;
            u32 ob = 0u;
            if (ci < CM1) {
                const float l = (batch == 0) ? ((lane == 63) ? sh1 : sh0) : sh1;
                if (l > thr) {                        // rare (~2% of lanes)
                    float sc = expf(l - mx) / es;     // exact
                    float4 rg = rrow[ci + 1];
                    float bx[4];
                    decode_clip(rg, w, h, cx, cy, fw, fh, bx);
                    valid = (sc > SCORE_T) && (bx[2] - bx[0] >= 1.0f) && (bx[3] - bx[1] >= 1.0f);
                    if (valid) {
                        ob = __float_as_uint(sc) | 0x80000000u;  // sc > 0 always
                        atomicAdd(&histrep[((size_t)img * NREP + rep) * NBUCKET + (ob >> 20)], 1u);
                    }
                }
            }
            const u64 bal = __ballot(valid);
            if (batch == 0) { w0 = bal; base1 = (u32)__popcll(bal); }
            else            { w1 = bal; }
            if (valid) {
                const u32 pre = (u32)__popcll(bal & ((1ull << lane) - 1ull));
                const u32 slot = (batch == 0) ? pre : (base1 + pre);   // <= 19 < NSLOT
                const u32 idx = (u32)n * CM1 + (u32)ci;
                clist[(size_t)pid * NSLOT + slot] = ((u64)ob << 32) | (u32)(~idx);
            }
        }
        if (lane == 0) {
            u64x2 v; v.x = w0; v.y = w1;
            reinterpret_cast<u64x2*>(cvalid)[pid] = v;
        }
    }
    // ---------------- decoupled tail: ticket ----------------
    __syncthreads();
    __threadfence();                                   // release my block's writes
    const int bimg = blockIdx.x / (NPROP / 4);         // 1000 blocks per image
    if (threadIdx.x == 0) tick = atomicAdd(&meta[128 + bimg * 32], 1u);
    __syncthreads();
    if (tick != (NPROP / 4) - 1) return;               // not last => done
    __threadfence();                                   // acquire others' writes
    // ---------------- k2 scan for image bimg (uint4 reads) ----------------
    {
        const int td = threadIdx.x;
        const int ln = td & 63, wv = td >> 6;
        const int lo = 4080 - td * 16;                 // buckets [lo, lo+15]; bk(k)=lo+15-k
        u32 cnt[16];
#pragma unroll
        for (int k = 0; k < 16; ++k) cnt[k] = 0;
        const u32* hb = histrep + (size_t)bimg * NREP * NBUCKET + lo;
#pragma unroll
        for (int r = 0; r < NREP; ++r) {
            const uint4* q = reinterpret_cast<const uint4*>(hb + (size_t)r * NBUCKET);
            uint4 a = q[0], b = q[1], c = q[2], d = q[3];
            cnt[15] += a.x; cnt[14] += a.y; cnt[13] += a.z; cnt[12] += a.w;
            cnt[11] += b.x; cnt[10] += b.y; cnt[9]  += b.z; cnt[8]  += b.w;
            cnt[7]  += c.x; cnt[6]  += c.y; cnt[5]  += c.z; cnt[4]  += c.w;
            cnt[3]  += d.x; cnt[2]  += d.y; cnt[1]  += d.z; cnt[0]  += d.w;
        }
        u32 tsum = 0;
#pragma unroll
        for (int k = 0; k < 16; ++k) tsum += cnt[k];
        u32 inc = tsum;
#pragma unroll
        for (int o = 1; o < 64; o <<= 1) { u32 t = __shfl_up(inc, o); if (ln >= o) inc += t; }
        if (td == 0) TbkS = 0u;
        if (ln == 63) wsum[wv] = inc;
        __syncthreads();
        u32 wbase = 0;
        for (int i = 0; i < wv; ++i) wbase += wsum[i];
        if (td == 255) Vs = wbase + inc;
        const u32 excl0 = wbase + inc - tsum;
        u32 sub[16];
        u32 excl = excl0;
#pragma unroll
        for (int k = 0; k < 16; ++k) {
            const int bk = 4095 - (td * 16 + k);
            start[bimg * NBUCKET + bk] = excl;
            histtot[bimg * NBUCKET + bk] = cnt[k];
            sub[k] = excl;
            if (cnt[k] > 0 && excl < KPRE && excl + cnt[k] >= KPRE) TbkS = (u32)bk;
            excl += cnt[k];
        }
#pragma unroll
        for (int r = 0; r < NREP; ++r) {
            const uint4* q = reinterpret_cast<const uint4*>(hb + (size_t)r * NBUCKET);
            uint4 a = q[0], b = q[1], c = q[2], d = q[3];
            u32 hh[16] = { d.w, d.z, d.y, d.x, c.w, c.z, c.y, c.x,
                           b.w, b.z, b.y, b.x, a.w, a.z, a.y, a.x };
#pragma unroll
            for (int k = 0; k < 16; ++k) {
                const int bk = 4095 - (td * 16 + k);
                startrep[((size_t)bimg * NBUCKET + bk) * NREP + r] = sub[k];
                sub[k] += hh[k];
            }
        }
        u32 qcnt = 0;
        {
            u32 e = excl0;
#pragma unroll
            for (int k = 0; k < 16; ++k) { if (cnt[k] >= 2 && e < KPRE) ++qcnt; e += cnt[k]; }
        }
        u32 qinc = qcnt;
#pragma unroll
        for (int o = 1; o < 64; o <<= 1) { u32 t = __shfl_up(qinc, o); if (ln >= o) qinc += t; }
        if (ln == 63) qws[wv] = qinc;
        __syncthreads();
        u32 qbase = 0;
        for (int i = 0; i < wv; ++i) qbase += qws[i];
        u32 qoff = qbase + qinc - qcnt;
        {
            u32 e = excl0;
#pragma unroll
            for (int k = 0; k < 16; ++k) {
                const int bk = 4095 - (td * 16 + k);
                if (cnt[k] >= 2 && e < KPRE && qoff < WLCAP) wlist[bimg * WLCAP + (qoff++)] = (u32)bk;
                e += cnt[k];
            }
        }
        if (td == 255) meta[bimg * 8 + 3] = qbase + qinc;   // worklist count
        __syncthreads();
        if (td == 0) {
            u32 V = Vs;
            meta[bimg * 8 + 0] = V;
            meta[bimg * 8 + 1] = TbkS;
            meta[bimg * 8 + 2] = (V < KPRE) ? (KPRE - V) : 0u;
        }
        __syncthreads();   // meta/startrep visible to whole block before k3
    }
    // ---------------- k3 compact for image bimg ----------------
    {
        const u32 cutoff = meta[bimg * 8 + 1];
        for (u32 n = (u32)threadIdx.x; n < NPROP; n += 256) {
            const u32 row = (u32)bimg * NPROP + n;
            const u64x2 vb = reinterpret_cast<const u64x2*>(cvalid)[row];
            const u32 rcnt = (u32)__popcll(vb.x) + (u32)__popcll(vb.y);
            const u32 rep = n & (NREP - 1);
            for (u32 slot = 0; slot < rcnt; ++slot) {
                const u64 e = clist[(size_t)row * NSLOT + slot];
                const u32 bk = (u32)(e >> 52);           // == (o >> 20)
                if (bk >= cutoff) {
                    const u32 pos = startrep[((size_t)bimg * NBUCKET + bk) * NREP + rep] +
                        atomicAdd(&bcntrep[((size_t)rep * BIMG + bimg) * NBUCKET + bk], 1u);
                    if (pos < SELCAP) sel[(size_t)bimg * SELCAP + pos] = e;
                }
            }
        }
        // k3b rare path (need>0, never in practice): wave 0
        if (threadIdx.x < 64) {
            const u32 need = meta[bimg * 8 + 2];
            if (need != 0) {
                const u32 V = meta[bimg * 8 + 0];
                const int lv = threadIdx.x;
                const u32 ORDN1 = 0x407FFFFFu;  // ord_of(-1.0f)
                u32 filled = 0;
                for (u32 b0 = 0; b0 < MCAND && filled < need; b0 += 64) {
                    const u32 idx = b0 + (u32)lv;
                    bool inv = false;
                    if (idx < MCAND) {
                        const u32 nn = (u32)(((u64)idx * 3054198967ull) >> 38);  // idx/90 exact
                        const u32 cq = idx - nn * 90u;
                        const u64 wb = cvalid[((size_t)bimg * NPROP + nn) * 2 + (cq >> 6)];
                        inv = ((wb >> (cq & 63)) & 1ull) == 0ull;
                    }
                    const u64 bal = __ballot(inv);
                    const u32 pre = (u32)__popcll(bal & ((1ull << lv) - 1ull));
                    if (inv && (filled + pre) < need)
                        sel[(size_t)bimg * SELCAP + V + filled + pre] =
                            ((u64)ORDN1 << 32) | (u32)(~idx);
                    filled += (u32)__popcll(bal);
                }
            }
        }
    }
}

// K4 (fused): r13 k4 sorts; last block per image runs k5 gather (round-2
// 256-thread version, validated) in its tail.
__global__ __launch_bounds__(256) void k4_fused(
    const u32* __restrict__ histtot, const u32* __restrict__ start,
    u32* __restrict__ meta, const u32* __restrict__ wlist, u64* __restrict__ sel,
    const float* __restrict__ reg, const float* __restrict__ props,
    const int* __restrict__ imh, const int* __restrict__ imw,
    float* __restrict__ tbox, float* __restrict__ tsb, float* __restrict__ tsc,
    int* __restrict__ tlb, u64* __restrict__ tvlb) {
    __shared__ u64 arr[4096];
    __shared__ u32 tick;
    __shared__ float wm[4];
    const int img = blockIdx.y;
    const int tid = threadIdx.x;
    const u32 wcount = meta[img * 8 + 3];
    // Phase A: big buckets (block-wide LDS bitonic)
    for (u32 wi = blockIdx.x; wi < wcount; wi += 64) {
        const u32 bk = (wi < WLCAP) ? wlist[img * WLCAP + wi] : 0u;
        u32 cnt = histtot[img * NBUCKET + bk];
        u32 st = start[img * NBUCKET + bk];
        if (cnt <= 64 || st >= KPRE) continue;
        if (st + cnt > SELCAP) cnt = SELCAP - st;
        if (cnt > 4096) cnt = 4096;
        int n = 1;
        while (n < (int)cnt) n <<= 1;
        u64* seg = sel + (size_t)img * SELCAP + st;
        for (int i = tid; i < n; i += 256) arr[i] = (i < (int)cnt) ? seg[i] : 0ull;
        __syncthreads();
        for (int k = 2; k <= n; k <<= 1)
            for (int j = k >> 1; j > 0; j >>= 1) {
                for (int i = tid; i < n; i += 256) {
                    int ixj = i ^ j;
                    if (ixj > i) {
                        u64 a = arr[i], b = arr[ixj];
                        bool swp = ((i & k) == 0) ? (a < b) : (a > b);
                        if (swp) { arr[i] = b; arr[ixj] = a; }
                    }
                }
                __syncthreads();
            }
        for (int i = tid; i < (int)cnt; i += 256) seg[i] = arr[i];
        __syncthreads();
    }
    // Phase B: small buckets, one wave each (in-register shfl bitonic)
    {
        const int wv = tid >> 6, lane = tid & 63;
        for (u32 wi = (u32)blockIdx.x * 4 + wv; wi < wcount; wi += 256) {
            const u32 bk = (wi < WLCAP) ? wlist[img * WLCAP + wi] : 0u;
            u32 cnt = histtot[img * NBUCKET + bk];
            u32 st = start[img * NBUCKET + bk];
            if (cnt < 2 || cnt > 64 || st >= KPRE) continue;
            if (st + cnt > SELCAP) cnt = SELCAP - st;
            u64* seg = sel + (size_t)img * SELCAP + st;
            u64 key = (lane < (int)cnt) ? seg[lane] : 0ull;
#pragma unroll
            for (int k = 2; k <= 64; k <<= 1) {
#pragma unroll
                for (int j = k >> 1; j > 0; j >>= 1) {
                    u64 other = __shfl_xor(key, j);
                    bool takeMax = ((lane & j) == 0) == ((lane & k) == 0);
                    u64 hi2 = (key > other) ? key : other;
                    u64 lo2 = (key > other) ? other : key;
                    key = takeMax ? hi2 : lo2;
                }
            }
            if (lane < (int)cnt) seg[lane] = key;
        }
    }
    // ---------------- decoupled tail: ticket ----------------
    __syncthreads();
    __threadfence();
    if (tid == 0) tick = atomicAdd(&meta[384 + img * 32], 1u);
    __syncthreads();
    if (tick != 63) return;
    __threadfence();
    // ---------------- k5 gather (round-2 256-thread body) ----------------
    {
        const float fw = (float)imw[0], fh = (float)imh[0];
        float bxv[8][4];
        int labv[8];
        float lm = -3.0e38f;
#pragma unroll
        for (int t = 0; t < 8; ++t) {
            int s = t * 256 + tid;
            u64 key = sel[(size_t)img * SELCAP + s];
            u32 o = (u32)(key >> 32);
            u32 idx = ~((u32)key);
            u32 b = (o & 0x80000000u) ? (o & 0x7FFFFFFFu) : ~o;
            float sc = __uint_as_float(b);               // exact masked score roundtrip
            u32 n = idx / CM1;
            int c = (int)(idx - n * CM1) + 1;
            int pid = img * NPROP + (int)n;
            float4 p = reinterpret_cast<const float4*>(props)[pid];
            float w = p.z - p.x, h = p.w - p.y;
            float cx = p.x + 0.5f * w, cy = p.y + 0.5f * h;
            float4 rg = reinterpret_cast<const float4*>(reg)[(size_t)pid * NCLS + c];
            decode_clip(rg, w, h, cx, cy, fw, fh, bxv[t]);
            labv[t] = c;
            lm = fmaxf(lm, fmaxf(fmaxf(bxv[t][0], bxv[t][1]), fmaxf(bxv[t][2], bxv[t][3])));
            reinterpret_cast<float4*>(tbox)[(size_t)img * KPRE + s] =
                make_float4(bxv[t][0], bxv[t][1], bxv[t][2], bxv[t][3]);
            tsc[(size_t)img * KPRE + s] = sc;
            tlb[(size_t)img * KPRE + s] = c;
            u64 bw = __ballot(sc > SCORE_T);             // word = s>>6 = t*4 + wave
            if ((tid & 63) == 0) tvlb[img * 32 + t * 4 + (tid >> 6)] = bw;
        }
#pragma unroll
        for (int o2 = 32; o2 > 0; o2 >>= 1) lm = fmaxf(lm, __shfl_xor(lm, o2));
        if ((tid & 63) == 0) wm[tid >> 6] = lm;
        __syncthreads();
        float mplus = fmaxf(fmaxf(wm[0], wm[1]), fmaxf(wm[2], wm[3])) + 1.0f;
#pragma unroll
        for (int t = 0; t < 8; ++t) {
            int s = t * 256 + tid;
            float off = (float)labv[t] * mplus;
            reinterpret_cast<float4*>(tsb)[(size_t)img * KPRE + s] =
                make_float4(bxv[t][0] + off, bxv[t][1] + off, bxv[t][2] + off, bxv[t][3] + off);
        }
    }
}

__device__ __forceinline__ u64 rdlane64(u64 v, int l) {
    u32 lo = (u32)__builtin_amdgcn_readlane((int)(u32)v, l);
    u32 hi = (u32)__builtin_amdgcn_readlane((int)(u32)(v >> 32), l);
    return ((u64)hi << 32) | lo;
}

__device__ __forceinline__ void g2l16(const void* g, void* l) {
    __builtin_amdgcn_global_load_lds(
        (const __attribute__((address_space(1))) void*)g,
        (__attribute__((address_space(3))) void*)l, 16, 0, 0);
}

// K6 (fused): 4 IoU tiles per block (one per wave, upper-triangular); last
// block per image runs k7 greedy-NMS+select on wave 0 in its tail.
__global__ __launch_bounds__(256) void k6_fused(
    const float* __restrict__ tsb, u64* __restrict__ mask, u32* __restrict__ meta,
    const u64* __restrict__ tvlb, const float* __restrict__ tsc,
    const float* __restrict__ tbox, const int* __restrict__ tlb,
    float* __restrict__ out) {
    __shared__ float4 cb[4][64];
    __shared__ float ca[4][64];
    __shared__ u64 smem[4096];           // k7 double buffer (tail only)
    __shared__ u32 tick;
    const int img = blockIdx.y;
    {
        const int wv = threadIdx.x >> 6, lane = threadIdx.x & 63;
        const u32 t = blockIdx.x * 4 + wv;             // < 528 (132*4)
        float f = sqrtf(8.0f * (float)t + 1.0f);
        u32 x = (u32)((f - 1.0f) * 0.5f);
        while ((x + 1) * (x + 2) / 2 <= t) ++x;
        while (x * (x + 1) / 2 > t) --x;
        const u32 y = t - x * (x + 1) / 2;             // x >= y guaranteed
        const int j0 = (int)x * 64;                    // column block
        const int i0 = (int)y * 64;                    // row block
        float4 c = reinterpret_cast<const float4*>(tsb)[(size_t)img * KPRE + j0 + lane];
        cb[wv][lane] = c;
        ca[wv][lane] = (c.z - c.x) * (c.w - c.y);
        __syncthreads();
        const int i = i0 + lane;
        float4 r = reinterpret_cast<const float4*>(tsb)[(size_t)img * KPRE + i];
        float ra = (r.z - r.x) * (r.w - r.y);
        u64 bits = 0ull;
#pragma unroll 8
        for (int jj = 0; jj < 64; ++jj) {
            int j = j0 + jj;
            float4 cc = cb[wv][jj];
            float wvv = fmaxf(fminf(r.z, cc.z) - fmaxf(r.x, cc.x), 0.0f);
            float hvv = fmaxf(fminf(r.w, cc.w) - fmaxf(r.y, cc.y), 0.0f);
            float inter = wvv * hvv;
            float iou = inter / ((ra + ca[wv][jj]) - inter);   // NaN compares false
            if ((iou > NMS_T) && (j > i)) bits |= (1ull << jj);
        }
        mask[((size_t)img * KPRE + i) * 32 + (j0 >> 6)] = bits;
    }
    // ---------------- decoupled tail: ticket ----------------
    __syncthreads();
    __threadfence();
    if (threadIdx.x == 0) tick = atomicAdd(&meta[640 + img * 32], 1u);
    __syncthreads();
    if (tick != 131) return;
    __threadfence();
    if (threadIdx.x >= 64) return;       // k7 is single-wave
    // ---------------- k7 greedy NMS + select (r13 verbatim) ----------------
    {
        const int lane = threadIdx.x;
        const int lg = lane >> 4;
        const int wlo = 2 * (lane & 15);
        const u64* mrow = mask + (size_t)img * KPRE * 32;

        u64 accx, accy, rp;
        {
            u64 nv = 0ull;
            if (lane < 32) nv = ~tvlb[img * 32 + lane];   // invalid word `lane`
            rp   = __shfl(nv, 0);
            accx = __shfl(nv, (lane & 15) * 2);
            accy = __shfl(nv, (lane & 15) * 2 + 1);
        }
        {
            const char* gsrc = (const char*)mrow + (size_t)lane * 16;
#pragma unroll
            for (int t = 0; t < 16; ++t)
                g2l16(gsrc + (size_t)t * 1024, (char*)smem + (size_t)t * 1024);
        }
        u64 diag = mrow[(size_t)lane * 32];

        u32 tk = 0;
        int bcut = 31;

#pragma unroll 1
        for (int b = 0; b < 32; ++b) {
            const size_t base32 = (size_t)b * 2048;
            const u64* cbuf = smem + (size_t)(b & 1) * 2048;

            u64 diagn = 0ull;
            if (b + 1 < 32) {
                diagn = mrow[base32 + 2048 + (size_t)lane * 32 + (b + 1)];
                const char* gsrc = (const char*)(mrow + base32 + 2048) + (size_t)lane * 16;
                char* nb_l = (char*)(smem + (size_t)((b + 1) & 1) * 2048);
#pragma unroll
                for (int t = 0; t < 16; ++t)
                    g2l16(gsrc + (size_t)t * 1024, nb_l + (size_t)t * 1024);
            }

            u64 A = rp;
#pragma unroll
            for (int u = 0; u < 64; ++u) {
                u64 row = rdlane64(diag, u);
                if (!((A >> u) & 1ull)) A |= row;
            }
            const u64 keptw = ~A;

            if (b + 1 < 32) asm volatile("s_waitcnt vmcnt(17)" ::: "memory");
            else            asm volatile("s_waitcnt vmcnt(0)" ::: "memory");

            const u64 gx = (wlo >= b) ? ~0ull : 0ull;       // sub-diagonal word gate
            const u64 gy = (wlo + 1 >= b) ? ~0ull : 0ull;

#define LDV(K) u64x2 v##K = *(const u64x2*)&cbuf[128 * (K) + 2 * lane];
#define PRV(K) { u32 nib = (u32)(keptw >> (4 * (K))) & 15u; \
                 u32 kb = (nib >> lg) & 1u; \
                 accx |= kb ? (v##K.x & gx) : 0ull; accy |= kb ? (v##K.y & gy) : 0ull; }
            LDV(0) LDV(1) LDV(2) LDV(3)
            LDV(4) LDV(5) LDV(6) LDV(7)     PRV(0) PRV(1) PRV(2) PRV(3)
            LDV(8) LDV(9) LDV(10) LDV(11)   PRV(4) PRV(5) PRV(6) PRV(7)
            LDV(12) LDV(13) LDV(14) LDV(15) PRV(8) PRV(9) PRV(10) PRV(11)
            PRV(12) PRV(13) PRV(14) PRV(15)
#undef LDV
#undef PRV

            tk += (u32)__popcll(keptw);
            if (tk >= (u32)DETS) { bcut = b; break; }

            const int nb2 = b + 1;
            if (nb2 < 32) {
                u64 asel = (nb2 & 1) ? accy : accx;
                const int sl = (nb2 >> 1) & 15;
                rp = rdlane64(asel, sl) | rdlane64(asel, sl + 16) |
                     rdlane64(asel, sl + 32) | rdlane64(asel, sl + 48);
            }
            diag = diagn;
        }

        asm volatile("s_waitcnt vmcnt(0)" ::: "memory");   // drain in-flight DMA

        accx |= __shfl_xor(accx, 16); accx |= __shfl_xor(accx, 32);
        accy |= __shfl_xor(accy, 16); accy |= __shfl_xor(accy, 32);

        u64 mxv = __shfl(accx, (lane >> 1) & 15);
        u64 myv = __shfl(accy, (lane >> 1) & 15);
        u64 kw = (lane & 1) ? ~myv : ~mxv;
        if (lane >= 32 || lane > bcut) kw = 0ull;

        u32 cnt = (u32)__popcll(kw);
        u32 inc = cnt;
#pragma unroll
        for (int o = 1; o < 64; o <<= 1) { u32 t = __shfl_up(inc, o); if (lane >= o) inc += t; }
        const u32 excl = inc - cnt;
        const u32 total = (u32)__shfl(inc, 63);

        float* ob0 = out + (size_t)img * DETS * 4;
        float* os0 = out + (size_t)BIMG * DETS * 4 + (size_t)img * DETS;
        float* ol0 = out + (size_t)BIMG * DETS * 5 + (size_t)img * DETS;

#pragma unroll
        for (int t = 0; t < 2; ++t) {
            u32 r = (u32)lane + (u32)t * 64;
            if (r < DETS && r >= total) {
                reinterpret_cast<float4*>(ob0)[r] = make_float4(0.f, 0.f, 0.f, 0.f);
                os0[r] = 0.0f;
                ol0[r] = -1.0f;
            }
        }
        u64 w = kw;
        u32 r = excl;
        while (w != 0ull && r < DETS) {
            int p = __ffsll((unsigned long long)w) - 1;
            w &= (w - 1ull);
            u32 s = (u32)lane * 64u + (u32)p;
            reinterpret_cast<float4*>(ob0)[r] =
                reinterpret_cast<const float4*>(tbox)[(size_t)img * KPRE + s];
            os0[r] = tsc[(size_t)img * KPRE + s];
            ol0[r] = (float)tlb[(size_t)img * KPRE + s];
            ++r;
        }
    }
}

extern "C" void kernel_launch(void* const* d_in, const int* in_sizes, int n_in,
                              void* d_out, int out_size, void* d_ws, size_t ws_size,
                              hipStream_t stream) {
    const float* logits = (const float*)d_in[0];
    const float* reg    = (const float*)d_in[1];
    const float* props  = (const float*)d_in[2];
    const int*   imh    = (const int*)d_in[3];
    const int*   imw    = (const int*)d_in[4];
    float* out = (float*)d_out;
    char* ws = (char*)d_ws;
    if (ws_size < WS_NEED) return;  // ~17.3 MB needed

    u32* histrep  = (u32*)(ws + HISTREP_OFF);
    u32* bcntrep  = (u32*)(ws + BCNTREP_OFF);
    u32* meta     = (u32*)(ws + META_OFF);
    u32* start    = (u32*)(ws + START_OFF);
    u32* histtot  = (u32*)(ws + HISTTOT_OFF);
    u32* startrep = (u32*)(ws + STARTREP_OFF);
    u64* sel  = (u64*)(ws + SEL_OFF);
    float* tbox = (float*)(ws + TBOX_OFF);
    float* tsb  = (float*)(ws + TSB_OFF);
    float* tsc  = (float*)(ws + TSC_OFF);
    int*   tlb  = (int*)(ws + TLB_OFF);
    u64*   tvlb = (u64*)(ws + TVLB_OFF);
    u32*   wlist = (u32*)(ws + WLIST_OFF);
    u64*   clist = (u64*)(ws + CLIST_OFF);
    u64*   cvalid = (u64*)(ws + CVALID_OFF);
    u64*   mask = (u64*)(ws + MASK_OFF);

    hipMemsetAsync(d_ws, 0, ZERO_BYTES, stream);  // histrep, bcntrep, meta+tickets

    k1_fused<<<BIMG * NPROP / 4, 256, 0, stream>>>(logits, reg, props, imh, imw,
                                                   histrep, clist, cvalid,
                                                   histtot, start, startrep, meta, wlist,
                                                   bcntrep, sel);
    k4_fused<<<dim3(64, BIMG), 256, 0, stream>>>(histtot, start, meta, wlist, sel,
                                                 reg, props, imh, imw,
                                                 tbox, tsb, tsc, tlb, tvlb);
    k6_fused<<<dim3(132, BIMG), 256, 0, stream>>>(tsb, mask, meta, tvlb, tsc, tbox, tlb, out);
}

// Round 6
// 304.735 us; speedup vs baseline: 3.6751x; 3.6751x over previous
//
#include <hip/hip_runtime.h>
#include <stdint.h>

typedef unsigned int u32;
typedef unsigned long long u64;
typedef __attribute__((ext_vector_type(2))) unsigned long long u64x2;

#define BIMG 8
#define NPROP 4000
#define NCLS 91
#define CM1 90
#define MCAND (NPROP * CM1)      // 360000 candidates per image
#define KPRE 2048
#define NBUCKET 4096
#define NREP 8                   // counter replicas (contention /8)
#define SELCAP 16384
#define NSLOT 32                 // per-row candidate slots (provable max 19)
#define DETS 100
#define WLCAP 2048               // worklist capacity per image
#define SCORE_T 0.05f
#define NMS_T 0.5f
#define BBOX_CLIP 4.135166556742356f   // log(1000/16)

// ---------------- workspace layout (r16 = r13 layout; meta now LDS-only) ----
#define HISTREP_OFF ((size_t)0)                                   // u32[8][8][4096]
#define BCNTREP_OFF (HISTREP_OFF + (size_t)NREP * BIMG * NBUCKET * 4)
#define META_OFF    (BCNTREP_OFF + (size_t)NREP * BIMG * NBUCKET * 4)  // unused, zeroed
#define ZERO_BYTES  (META_OFF + 4096)
#define START_OFF   (ZERO_BYTES)                                  // u32[8][4096]
#define HISTTOT_OFF (START_OFF + (size_t)BIMG * NBUCKET * 4)      // u32[8][4096]
#define STARTREP_OFF (HISTTOT_OFF + (size_t)BIMG * NBUCKET * 4)   // u32[8][4096][8]
#define SEL_OFF     (STARTREP_OFF + (size_t)NREP * BIMG * NBUCKET * 4) // u64[8][SELCAP]
#define TBOX_OFF    (SEL_OFF + (size_t)BIMG * SELCAP * 8)         // f32[8][2048][4]
#define TSB_OFF     (TBOX_OFF + (size_t)BIMG * KPRE * 16)         // f32[8][2048][4]
#define TSC_OFF     (TSB_OFF + (size_t)BIMG * KPRE * 16)          // f32[8][2048]
#define TLB_OFF     (TSC_OFF + (size_t)BIMG * KPRE * 4)           // i32[8][2048]
#define TVLB_OFF    (TLB_OFF + (size_t)BIMG * KPRE * 4)           // u64[8][32]
#define WLIST_OFF   (TVLB_OFF + (size_t)BIMG * 32 * 8)            // u32[8][WLCAP]
#define CLIST_OFF   (WLIST_OFF + (size_t)BIMG * WLCAP * 4)        // u64[32000][NSLOT]
#define CVALID_OFF  (CLIST_OFF + (size_t)BIMG * NPROP * NSLOT * 8) // u64[32000][2]
#define MASK_OFF    (CVALID_OFF + (size_t)BIMG * NPROP * 2 * 8)   // u64[8][2048][32]
#define WS_NEED     (MASK_OFF + (size_t)BIMG * KPRE * 32 * 8)     // ~17.3 MB

__device__ __forceinline__ void decode_clip(const float4 rg, const float w, const float h,
                                            const float cx, const float cy,
                                            const float fw, const float fh, float bx[4]) {
    float dx = rg.x / 10.0f;
    float dy = rg.y / 10.0f;
    float dw = fminf(rg.z / 5.0f, BBOX_CLIP);
    float dh = fminf(rg.w / 5.0f, BBOX_CLIP);
    float pcx = dx * w + cx;
    float pcy = dy * h + cy;
    float pw  = expf(dw) * w;
    float phh = expf(dh) * h;
    bx[0] = fminf(fmaxf(pcx - 0.5f * pw,  0.0f), fw);
    bx[1] = fminf(fmaxf(pcy - 0.5f * phh, 0.0f), fh);
    bx[2] = fminf(fmaxf(pcx + 0.5f * pw,  0.0f), fw);
    bx[3] = fminf(fmaxf(pcy + 0.5f * phh, 0.0f), fh);
}

// K1: r13 verbatim (validated; 20 VGPR, no contended atomics, no tail).
__global__ __launch_bounds__(256) void k1_score_hist(
    const float* __restrict__ logits, const float* __restrict__ reg,
    const float* __restrict__ props, const int* __restrict__ imh, const int* __restrict__ imw,
    u32* __restrict__ histrep, u64* __restrict__ clist, u64* __restrict__ cvalid) {
    const int lane = threadIdx.x & 63;
    const int pid = blockIdx.x * 4 + (threadIdx.x >> 6);
    if (pid >= BIMG * NPROP) return;
    const int img = pid / NPROP;
    const float fw = (float)imw[0], fh = (float)imh[0];
    const float* lrow = logits + (size_t)pid * NCLS;
    float v0 = lrow[lane];
    float v1 = (lane < 27) ? lrow[lane + 64] : -3.0e38f;
    float mx = fmaxf(v0, v1);
#pragma unroll
    for (int o = 32; o > 0; o >>= 1) mx = fmaxf(mx, __shfl_xor(mx, o));
    float es = expf(v0 - mx) + ((lane < 27) ? expf(v1 - mx) : 0.0f);
#pragma unroll
    for (int o = 32; o > 0; o >>= 1) es += __shfl_xor(es, o);
    const float thr = mx + logf(es) - 2.9967323f;   // ln(0.05) - 1e-3 margin
    float4 p = reinterpret_cast<const float4*>(props)[pid];
    const float w = p.z - p.x, h = p.w - p.y;
    const float cx = p.x + 0.5f * w, cy = p.y + 0.5f * h;
    const float4* rrow = reinterpret_cast<const float4*>(reg) + (size_t)pid * NCLS;
    const int n = pid - img * NPROP;
    const int rep = n & (NREP - 1);
    const float sh0 = __shfl(v0, (lane + 1) & 63);
    const float sh1 = __shfl(v1, (lane + 1) & 63);
    u64 w0 = 0ull, w1 = 0ull;
    u32 base1 = 0;
#pragma unroll
    for (int batch = 0; batch < 2; ++batch) {
        const int ci = lane + batch * 64;
        bool valid = false;
        u32 ob = 0u;
        if (ci < CM1) {
            const float l = (batch == 0) ? ((lane == 63) ? sh1 : sh0) : sh1;
            if (l > thr) {                        // rare (~2% of lanes)
                float sc = expf(l - mx) / es;     // exact
                float4 rg = rrow[ci + 1];
                float bx[4];
                decode_clip(rg, w, h, cx, cy, fw, fh, bx);
                valid = (sc > SCORE_T) && (bx[2] - bx[0] >= 1.0f) && (bx[3] - bx[1] >= 1.0f);
                if (valid) {
                    ob = __float_as_uint(sc) | 0x80000000u;  // sc > 0 always
                    atomicAdd(&histrep[((size_t)img * NREP + rep) * NBUCKET + (ob >> 20)], 1u);
                }
            }
        }
        const u64 bal = __ballot(valid);
        if (batch == 0) { w0 = bal; base1 = (u32)__popcll(bal); }
        else            { w1 = bal; }
        if (valid) {
            const u32 pre = (u32)__popcll(bal & ((1ull << lane) - 1ull));
            const u32 slot = (batch == 0) ? pre : (base1 + pre);   // <= 19 < NSLOT
            const u32 idx = (u32)n * CM1 + (u32)ci;
            clist[(size_t)pid * NSLOT + slot] = ((u64)ob << 32) | (u32)(~idx);
        }
    }
    if (lane == 0) {
        u64x2 v; v.x = w0; v.y = w1;
        reinterpret_cast<u64x2*>(cvalid)[pid] = v;
    }
}

// KMID8: one block per image runs scan -> compact -> sorts -> gather with
// plain __syncthreads between phases (per-image deps are block-internal; the
// r15 run validated these exact bodies, only the cross-block ticket was bad).
// No grid-wide sync, no contended atomics. meta lives in LDS.
__global__ __launch_bounds__(512) void kmid8(
    const u32* __restrict__ histrep, u32* __restrict__ histtot,
    u32* __restrict__ start, u32* __restrict__ startrep, u32* __restrict__ wlist,
    const u64* __restrict__ clist, const u64* __restrict__ cvalid,
    u32* __restrict__ bcntrep, u64* __restrict__ sel,
    const float* __restrict__ reg, const float* __restrict__ props,
    const int* __restrict__ imh, const int* __restrict__ imw,
    float* __restrict__ tbox, float* __restrict__ tsb, float* __restrict__ tsc,
    int* __restrict__ tlb, u64* __restrict__ tvlb) {
    __shared__ u64 arr[4096];            // 32 KB sort buffer
    __shared__ u32 wsum[4], qws[4];
    __shared__ u32 TbkS, Vs, WcS;
    __shared__ float wm[8];
    const int img = blockIdx.x;
    const int tid = threadIdx.x;
    const int ln = tid & 63, wv = tid >> 6;
    const bool act = tid < 256;          // scan runs on waves 0..3

    // ---------------- phase 1: scan (r15-validated uint4 body) ----------------
    u32 cnt[16]; u32 tsum = 0, inc = 0, excl0 = 0, qcnt = 0, qinc = 0;
    if (act) {
#pragma unroll
        for (int k = 0; k < 16; ++k) cnt[k] = 0;
        const int lo = 4080 - tid * 16;  // buckets [lo, lo+15]; bk(k) = lo+15-k
        const u32* hb = histrep + (size_t)img * NREP * NBUCKET + lo;
#pragma unroll
        for (int r = 0; r < NREP; ++r) {
            const uint4* q = reinterpret_cast<const uint4*>(hb + (size_t)r * NBUCKET);
            uint4 a = q[0], b = q[1], c = q[2], d = q[3];
            cnt[15] += a.x; cnt[14] += a.y; cnt[13] += a.z; cnt[12] += a.w;
            cnt[11] += b.x; cnt[10] += b.y; cnt[9]  += b.z; cnt[8]  += b.w;
            cnt[7]  += c.x; cnt[6]  += c.y; cnt[5]  += c.z; cnt[4]  += c.w;
            cnt[3]  += d.x; cnt[2]  += d.y; cnt[1]  += d.z; cnt[0]  += d.w;
        }
#pragma unroll
        for (int k = 0; k < 16; ++k) tsum += cnt[k];
        inc = tsum;
#pragma unroll
        for (int o = 1; o < 64; o <<= 1) { u32 t = __shfl_up(inc, o); if (ln >= o) inc += t; }
        if (tid == 0) TbkS = 0u;
        if (ln == 63) wsum[wv] = inc;
    }
    __syncthreads();
    if (act) {
        u32 wbase = 0;
        for (int i = 0; i < wv; ++i) wbase += wsum[i];
        if (tid == 255) Vs = wbase + inc;
        excl0 = wbase + inc - tsum;
        u32 sub[16];
        u32 excl = excl0;
#pragma unroll
        for (int k = 0; k < 16; ++k) {
            const int bk = 4095 - (tid * 16 + k);
            start[img * NBUCKET + bk] = excl;
            histtot[img * NBUCKET + bk] = cnt[k];
            sub[k] = excl;
            if (cnt[k] > 0 && excl < KPRE && excl + cnt[k] >= KPRE) TbkS = (u32)bk;
            excl += cnt[k];
        }
        const int lo = 4080 - tid * 16;
        const u32* hb = histrep + (size_t)img * NREP * NBUCKET + lo;
#pragma unroll
        for (int r = 0; r < NREP; ++r) {
            const uint4* q = reinterpret_cast<const uint4*>(hb + (size_t)r * NBUCKET);
            uint4 a = q[0], b = q[1], c = q[2], d = q[3];
            u32 hh[16] = { d.w, d.z, d.y, d.x, c.w, c.z, c.y, c.x,
                           b.w, b.z, b.y, b.x, a.w, a.z, a.y, a.x };
#pragma unroll
            for (int k = 0; k < 16; ++k) {
                const int bk = 4095 - (tid * 16 + k);
                startrep[((size_t)img * NBUCKET + bk) * NREP + r] = sub[k];
                sub[k] += hh[k];
            }
        }
        {
            u32 e = excl0;
#pragma unroll
            for (int k = 0; k < 16; ++k) { if (cnt[k] >= 2 && e < KPRE) ++qcnt; e += cnt[k]; }
        }
        qinc = qcnt;
#pragma unroll
        for (int o = 1; o < 64; o <<= 1) { u32 t = __shfl_up(qinc, o); if (ln >= o) qinc += t; }
        if (ln == 63) qws[wv] = qinc;
    }
    __syncthreads();
    if (act) {
        u32 qbase = 0;
        for (int i = 0; i < wv; ++i) qbase += qws[i];
        u32 qoff = qbase + qinc - qcnt;
        u32 e = excl0;
#pragma unroll
        for (int k = 0; k < 16; ++k) {
            const int bk = 4095 - (tid * 16 + k);
            if (cnt[k] >= 2 && e < KPRE && qoff < WLCAP) wlist[img * WLCAP + (qoff++)] = (u32)bk;
            e += cnt[k];
        }
        if (tid == 255) WcS = qbase + qinc;
    }
    __syncthreads();

    // ---------------- phase 2: compact (r15-validated body; all 512 thr) ------
    {
        const u32 cutoff = TbkS;
        for (u32 n = (u32)tid; n < NPROP; n += 512) {
            const u32 row = (u32)img * NPROP + n;
            const u64x2 vb = reinterpret_cast<const u64x2*>(cvalid)[row];
            const u32 rcnt = (u32)__popcll(vb.x) + (u32)__popcll(vb.y);
            const u32 rep = n & (NREP - 1);
            for (u32 slot = 0; slot < rcnt; ++slot) {
                const u64 e = clist[(size_t)row * NSLOT + slot];
                const u32 bk = (u32)(e >> 52);           // == (o >> 20)
                if (bk >= cutoff) {
                    const u32 pos = startrep[((size_t)img * NBUCKET + bk) * NREP + rep] +
                        atomicAdd(&bcntrep[((size_t)rep * BIMG + img) * NBUCKET + bk], 1u);
                    if (pos < SELCAP) sel[(size_t)img * SELCAP + pos] = e;
                }
            }
        }
        // k3b rare path (need>0, never in practice): wave 0 only
        if (tid < 64) {
            const u32 V = Vs;
            const u32 need = (V < KPRE) ? (KPRE - V) : 0u;
            if (need != 0) {
                const int lv = tid;
                const u32 ORDN1 = 0x407FFFFFu;  // ord_of(-1.0f)
                u32 filled = 0;
                for (u32 b0 = 0; b0 < MCAND && filled < need; b0 += 64) {
                    const u32 idx = b0 + (u32)lv;
                    bool inv = false;
                    if (idx < MCAND) {
                        const u32 nn = (u32)(((u64)idx * 3054198967ull) >> 38);  // idx/90 exact
                        const u32 cq = idx - nn * 90u;
                        const u64 wb = cvalid[((size_t)img * NPROP + nn) * 2 + (cq >> 6)];
                        inv = ((wb >> (cq & 63)) & 1ull) == 0ull;
                    }
                    const u64 bal = __ballot(inv);
                    const u32 pre = (u32)__popcll(bal & ((1ull << lv) - 1ull));
                    if (inv && (filled + pre) < need)
                        sel[(size_t)img * SELCAP + V + filled + pre] =
                            ((u64)ORDN1 << 32) | (u32)(~idx);
                    filled += (u32)__popcll(bal);
                }
            }
        }
    }
    __syncthreads();

    // ---------------- phase 3a: big-bucket sorts (block-wide, sequential) -----
    const u32 wcount = WcS;
    for (u32 wi = 0; wi < wcount; ++wi) {
        const u32 bk = (wi < WLCAP) ? wlist[img * WLCAP + wi] : 0u;
        u32 cnt2 = histtot[img * NBUCKET + bk];
        u32 st = start[img * NBUCKET + bk];
        if (cnt2 <= 64 || st >= KPRE) continue;          // uniform branch
        if (st + cnt2 > SELCAP) cnt2 = SELCAP - st;
        if (cnt2 > 4096) cnt2 = 4096;
        int n = 1;
        while (n < (int)cnt2) n <<= 1;
        u64* seg = sel + (size_t)img * SELCAP + st;
        for (int i = tid; i < n; i += 512) arr[i] = (i < (int)cnt2) ? seg[i] : 0ull;
        __syncthreads();
        for (int k = 2; k <= n; k <<= 1)
            for (int j = k >> 1; j > 0; j >>= 1) {
                for (int i = tid; i < n; i += 512) {
                    int ixj = i ^ j;
                    if (ixj > i) {
                        u64 a = arr[i], b = arr[ixj];
                        bool swp = ((i & k) == 0) ? (a < b) : (a > b);
                        if (swp) { arr[i] = b; arr[ixj] = a; }
                    }
                }
                __syncthreads();
            }
        for (int i = tid; i < (int)cnt2; i += 512) seg[i] = arr[i];
        __syncthreads();
    }
    // ---------------- phase 3b: small-bucket sorts (one wave each) ------------
    for (u32 wi = (u32)wv; wi < wcount; wi += 8) {
        const u32 bk = (wi < WLCAP) ? wlist[img * WLCAP + wi] : 0u;
        u32 cnt2 = histtot[img * NBUCKET + bk];
        u32 st = start[img * NBUCKET + bk];
        if (cnt2 < 2 || cnt2 > 64 || st >= KPRE) continue;
        if (st + cnt2 > SELCAP) cnt2 = SELCAP - st;
        u64* seg = sel + (size_t)img * SELCAP + st;
        u64 key = (ln < (int)cnt2) ? seg[ln] : 0ull;     // 0 sinks (real keys have MSB)
#pragma unroll
        for (int k = 2; k <= 64; k <<= 1) {
#pragma unroll
            for (int j = k >> 1; j > 0; j >>= 1) {
                u64 other = __shfl_xor(key, j);
                bool takeMax = ((ln & j) == 0) == ((ln & k) == 0);
                u64 hi2 = (key > other) ? key : other;
                u64 lo2 = (key > other) ? other : key;
                key = takeMax ? hi2 : lo2;
            }
        }
        if (ln < (int)cnt2) seg[ln] = key;
    }
    __syncthreads();

    // ---------------- phase 4: gather (r13 1024-thr body adapted to 512) ------
    {
        const float fw = (float)imw[0], fh = (float)imh[0];
        float bxv[4][4];
        int labv[4];
        float lm = -3.0e38f;
#pragma unroll
        for (int t = 0; t < 4; ++t) {
            int s = t * 512 + tid;
            u64 key = sel[(size_t)img * SELCAP + s];
            u32 o = (u32)(key >> 32);
            u32 idx = ~((u32)key);
            u32 b = (o & 0x80000000u) ? (o & 0x7FFFFFFFu) : ~o;
            float sc = __uint_as_float(b);               // exact masked score roundtrip
            u32 n = idx / CM1;
            int c = (int)(idx - n * CM1) + 1;
            int pid = img * NPROP + (int)n;
            float4 p = reinterpret_cast<const float4*>(props)[pid];
            float w = p.z - p.x, h = p.w - p.y;
            float cx = p.x + 0.5f * w, cy = p.y + 0.5f * h;
            float4 rg = reinterpret_cast<const float4*>(reg)[(size_t)pid * NCLS + c];
            decode_clip(rg, w, h, cx, cy, fw, fh, bxv[t]);
            labv[t] = c;
            lm = fmaxf(lm, fmaxf(fmaxf(bxv[t][0], bxv[t][1]), fmaxf(bxv[t][2], bxv[t][3])));
            reinterpret_cast<float4*>(tbox)[(size_t)img * KPRE + s] =
                make_float4(bxv[t][0], bxv[t][1], bxv[t][2], bxv[t][3]);
            tsc[(size_t)img * KPRE + s] = sc;
            tlb[(size_t)img * KPRE + s] = c;
            u64 bw = __ballot(sc > SCORE_T);             // word = s>>6 = t*8 + wv
            if (ln == 0) tvlb[img * 32 + t * 8 + wv] = bw;
        }
#pragma unroll
        for (int o2 = 32; o2 > 0; o2 >>= 1) lm = fmaxf(lm, __shfl_xor(lm, o2));
        if (ln == 0) wm[wv] = lm;
        __syncthreads();
        float m = wm[0];
#pragma unroll
        for (int i = 1; i < 8; ++i) m = fmaxf(m, wm[i]);
        const float mplus = m + 1.0f;
#pragma unroll
        for (int t = 0; t < 4; ++t) {
            int s = t * 512 + tid;
            float off = (float)labv[t] * mplus;
            reinterpret_cast<float4*>(tsb)[(size_t)img * KPRE + s] =
                make_float4(bxv[t][0] + off, bxv[t][1] + off, bxv[t][2] + off, bxv[t][3] + off);
        }
    }
}

// K6: r15-validated body (4 upper-triangular tiles per 256-thr block), no tail.
__global__ __launch_bounds__(256) void k6_mask(
    const float* __restrict__ tsb, u64* __restrict__ mask) {
    const int img = blockIdx.y;
    const int wv = threadIdx.x >> 6, lane = threadIdx.x & 63;
    const u32 t = blockIdx.x * 4 + wv;             // < 528 (132*4)
    float f = sqrtf(8.0f * (float)t + 1.0f);
    u32 x = (u32)((f - 1.0f) * 0.5f);
    while ((x + 1) * (x + 2) / 2 <= t) ++x;
    while (x * (x + 1) / 2 > t) --x;
    const u32 y = t - x * (x + 1) / 2;             // x >= y guaranteed
    const int j0 = (int)x * 64;                    // column block
    const int i0 = (int)y * 64;                    // row block
    __shared__ float4 cb[4][64];
    __shared__ float ca[4][64];
    float4 c = reinterpret_cast<const float4*>(tsb)[(size_t)img * KPRE + j0 + lane];
    cb[wv][lane] = c;
    ca[wv][lane] = (c.z - c.x) * (c.w - c.y);
    __syncthreads();
    const int i = i0 + lane;
    float4 r = reinterpret_cast<const float4*>(tsb)[(size_t)img * KPRE + i];
    float ra = (r.z - r.x) * (r.w - r.y);
    u64 bits = 0ull;
#pragma unroll 8
    for (int jj = 0; jj < 64; ++jj) {
        int j = j0 + jj;
        float4 cc = cb[wv][jj];
        float wvv = fmaxf(fminf(r.z, cc.z) - fmaxf(r.x, cc.x), 0.0f);
        float hvv = fmaxf(fminf(r.w, cc.w) - fmaxf(r.y, cc.y), 0.0f);
        float inter = wvv * hvv;
        float iou = inter / ((ra + ca[wv][jj]) - inter);   // NaN compares false
        if ((iou > NMS_T) && (j > i)) bits |= (1ull << jj);
    }
    mask[((size_t)img * KPRE + i) * 32 + (j0 >> 6)] = bits;
}

// K7+K8 fused greedy NMS + select (r13 verbatim, sub-diagonal gates).
__device__ __forceinline__ u64 rdlane64(u64 v, int l) {
    u32 lo = (u32)__builtin_amdgcn_readlane((int)(u32)v, l);
    u32 hi = (u32)__builtin_amdgcn_readlane((int)(u32)(v >> 32), l);
    return ((u64)hi << 32) | lo;
}

__device__ __forceinline__ void g2l16(const void* g, void* l) {
    __builtin_amdgcn_global_load_lds(
        (const __attribute__((address_space(1))) void*)g,
        (__attribute__((address_space(3))) void*)l, 16, 0, 0);
}

__global__ __launch_bounds__(64) void k7_nms_sel(
    const u64* __restrict__ mask, const u64* __restrict__ tvlb,
    const float* __restrict__ tsc, const float* __restrict__ tbox,
    const int* __restrict__ tlb, float* __restrict__ out) {
    __shared__ u64 smem[4096];           // 2 x 16 KB double buffer
    const int img = blockIdx.x;
    const int lane = threadIdx.x;
    const int lg = lane >> 4;
    const int wlo = 2 * (lane & 15);
    const u64* mrow = mask + (size_t)img * KPRE * 32;

    u64 accx, accy, rp;
    {
        u64 nv = 0ull;
        if (lane < 32) nv = ~tvlb[img * 32 + lane];   // invalid word `lane`
        rp   = __shfl(nv, 0);
        accx = __shfl(nv, (lane & 15) * 2);
        accy = __shfl(nv, (lane & 15) * 2 + 1);
    }

    {
        const char* gsrc = (const char*)mrow + (size_t)lane * 16;
#pragma unroll
        for (int t = 0; t < 16; ++t)
            g2l16(gsrc + (size_t)t * 1024, (char*)smem + (size_t)t * 1024);
    }
    u64 diag = mrow[(size_t)lane * 32];

    u32 tk = 0;
    int bcut = 31;

#pragma unroll 1
    for (int b = 0; b < 32; ++b) {
        const size_t base32 = (size_t)b * 2048;
        const u64* cbuf = smem + (size_t)(b & 1) * 2048;

        u64 diagn = 0ull;
        if (b + 1 < 32) {
            diagn = mrow[base32 + 2048 + (size_t)lane * 32 + (b + 1)];
            const char* gsrc = (const char*)(mrow + base32 + 2048) + (size_t)lane * 16;
            char* nb_l = (char*)(smem + (size_t)((b + 1) & 1) * 2048);
#pragma unroll
            for (int t = 0; t < 16; ++t)
                g2l16(gsrc + (size_t)t * 1024, nb_l + (size_t)t * 1024);
        }

        u64 A = rp;
#pragma unroll
        for (int u = 0; u < 64; ++u) {
            u64 row = rdlane64(diag, u);
            if (!((A >> u) & 1ull)) A |= row;
        }
        const u64 keptw = ~A;

        if (b + 1 < 32) asm volatile("s_waitcnt vmcnt(17)" ::: "memory");
        else            asm volatile("s_waitcnt vmcnt(0)" ::: "memory");

        const u64 gx = (wlo >= b) ? ~0ull : 0ull;       // sub-diagonal word gate
        const u64 gy = (wlo + 1 >= b) ? ~0ull : 0ull;

#define LDV(K) u64x2 v##K = *(const u64x2*)&cbuf[128 * (K) + 2 * lane];
#define PRV(K) { u32 nib = (u32)(keptw >> (4 * (K))) & 15u; \
                 u32 kb = (nib >> lg) & 1u; \
                 accx |= kb ? (v##K.x & gx) : 0ull; accy |= kb ? (v##K.y & gy) : 0ull; }
        LDV(0) LDV(1) LDV(2) LDV(3)
        LDV(4) LDV(5) LDV(6) LDV(7)     PRV(0) PRV(1) PRV(2) PRV(3)
        LDV(8) LDV(9) LDV(10) LDV(11)   PRV(4) PRV(5) PRV(6) PRV(7)
        LDV(12) LDV(13) LDV(14) LDV(15) PRV(8) PRV(9) PRV(10) PRV(11)
        PRV(12) PRV(13) PRV(14) PRV(15)
#undef LDV
#undef PRV

        tk += (u32)__popcll(keptw);
        if (tk >= (u32)DETS) { bcut = b; break; }

        const int nb2 = b + 1;
        if (nb2 < 32) {
            u64 asel = (nb2 & 1) ? accy : accx;
            const int sl = (nb2 >> 1) & 15;
            rp = rdlane64(asel, sl) | rdlane64(asel, sl + 16) |
                 rdlane64(asel, sl + 32) | rdlane64(asel, sl + 48);
        }
        diag = diagn;
    }

    asm volatile("s_waitcnt vmcnt(0)" ::: "memory");   // drain in-flight DMA

    accx |= __shfl_xor(accx, 16); accx |= __shfl_xor(accx, 32);
    accy |= __shfl_xor(accy, 16); accy |= __shfl_xor(accy, 32);

    u64 mxv = __shfl(accx, (lane >> 1) & 15);
    u64 myv = __shfl(accy, (lane >> 1) & 15);
    u64 kw = (lane & 1) ? ~myv : ~mxv;
    if (lane >= 32 || lane > bcut) kw = 0ull;

    u32 cnt = (u32)__popcll(kw);
    u32 inc = cnt;
#pragma unroll
    for (int o = 1; o < 64; o <<= 1) { u32 t = __shfl_up(inc, o); if (lane >= o) inc += t; }
    const u32 excl = inc - cnt;
    const u32 total = (u32)__shfl(inc, 63);

    float* ob0 = out + (size_t)img * DETS * 4;
    float* os0 = out + (size_t)BIMG * DETS * 4 + (size_t)img * DETS;
    float* ol0 = out + (size_t)BIMG * DETS * 5 + (size_t)img * DETS;

#pragma unroll
    for (int t = 0; t < 2; ++t) {
        u32 r = (u32)lane + (u32)t * 64;
        if (r < DETS && r >= total) {
            reinterpret_cast<float4*>(ob0)[r] = make_float4(0.f, 0.f, 0.f, 0.f);
            os0[r] = 0.0f;
            ol0[r] = -1.0f;
        }
    }
    u64 w = kw;
    u32 r = excl;
    while (w != 0ull && r < DETS) {
        int p = __ffsll((unsigned long long)w) - 1;
        w &= (w - 1ull);
        u32 s = (u32)lane * 64u + (u32)p;
        reinterpret_cast<float4*>(ob0)[r] =
            reinterpret_cast<const float4*>(tbox)[(size_t)img * KPRE + s];
        os0[r] = tsc[(size_t)img * KPRE + s];
        ol0[r] = (float)tlb[(size_t)img * KPRE + s];
        ++r;
    }
}

extern "C" void kernel_launch(void* const* d_in, const int* in_sizes, int n_in,
                              void* d_out, int out_size, void* d_ws, size_t ws_size,
                              hipStream_t stream) {
    const float* logits = (const float*)d_in[0];
    const float* reg    = (const float*)d_in[1];
    const float* props  = (const float*)d_in[2];
    const int*   imh    = (const int*)d_in[3];
    const int*   imw    = (const int*)d_in[4];
    float* out = (float*)d_out;
    char* ws = (char*)d_ws;
    if (ws_size < WS_NEED) return;  // ~17.3 MB needed

    u32* histrep  = (u32*)(ws + HISTREP_OFF);
    u32* bcntrep  = (u32*)(ws + BCNTREP_OFF);
    u32* start    = (u32*)(ws + START_OFF);
    u32* histtot  = (u32*)(ws + HISTTOT_OFF);
    u32* startrep = (u32*)(ws + STARTREP_OFF);
    u64* sel  = (u64*)(ws + SEL_OFF);
    float* tbox = (float*)(ws + TBOX_OFF);
    float* tsb  = (float*)(ws + TSB_OFF);
    float* tsc  = (float*)(ws + TSC_OFF);
    int*   tlb  = (int*)(ws + TLB_OFF);
    u64*   tvlb = (u64*)(ws + TVLB_OFF);
    u32*   wlist = (u32*)(ws + WLIST_OFF);
    u64*   clist = (u64*)(ws + CLIST_OFF);
    u64*   cvalid = (u64*)(ws + CVALID_OFF);
    u64*   mask = (u64*)(ws + MASK_OFF);

    hipMemsetAsync(d_ws, 0, ZERO_BYTES, stream);  // histrep, bcntrep

    k1_score_hist<<<BIMG * NPROP / 4, 256, 0, stream>>>(logits, reg, props, imh, imw,
                                                        histrep, clist, cvalid);
    kmid8<<<BIMG, 512, 0, stream>>>(histrep, histtot, start, startrep, wlist,
                                    clist, cvalid, bcntrep, sel,
                                    reg, props, imh, imw,
                                    tbox, tsb, tsc, tlb, tvlb);
    k6_mask<<<dim3(132, BIMG), 256, 0, stream>>>(tsb, mask);
    k7_nms_sel<<<BIMG, 64, 0, stream>>>(mask, tvlb, tsc, tbox, tlb, out);
}

// Round 7
// 227.641 us; speedup vs baseline: 4.9197x; 1.3387x over previous
//
#include <hip/hip_runtime.h>
#include <stdint.h>

typedef unsigned int u32;
typedef unsigned long long u64;
typedef __attribute__((ext_vector_type(2))) unsigned long long u64x2;

#define BIMG 8
#define NPROP 4000
#define NCLS 91
#define CM1 90
#define MCAND (NPROP * CM1)      // 360000 candidates per image
#define KPRE 2048
#define NBUCKET 4096
#define NREP 8                   // counter replicas (contention /8)
#define SELCAP 16384
#define NSLOT 32                 // per-row candidate slots (provable max 19)
#define DETS 100
#define WLCAP 2048               // worklist capacity per image
#define SCORE_T 0.05f
#define NMS_T 0.5f
#define BBOX_CLIP 4.135166556742356f   // log(1000/16)

// ---------------- workspace layout (r17 = r13 layout) ----------------
// histrep: [img][rep][bucket]; startrep: [img][bucket][rep]; bcntrep: [rep][img][bucket]
#define HISTREP_OFF ((size_t)0)                                   // u32[8][8][4096]
#define BCNTREP_OFF (HISTREP_OFF + (size_t)NREP * BIMG * NBUCKET * 4)
#define META_OFF    (BCNTREP_OFF + (size_t)NREP * BIMG * NBUCKET * 4)  // u32[8][8]
#define ZERO_BYTES  (META_OFF + 4096)
#define START_OFF   (ZERO_BYTES)                                  // u32[8][4096]
#define HISTTOT_OFF (START_OFF + (size_t)BIMG * NBUCKET * 4)      // u32[8][4096]
#define STARTREP_OFF (HISTTOT_OFF + (size_t)BIMG * NBUCKET * 4)   // u32[8][4096][8]
#define SEL_OFF     (STARTREP_OFF + (size_t)NREP * BIMG * NBUCKET * 4) // u64[8][SELCAP]
#define TBOX_OFF    (SEL_OFF + (size_t)BIMG * SELCAP * 8)         // f32[8][2048][4]
#define TSB_OFF     (TBOX_OFF + (size_t)BIMG * KPRE * 16)         // f32[8][2048][4]
#define TSC_OFF     (TSB_OFF + (size_t)BIMG * KPRE * 16)          // f32[8][2048]
#define TLB_OFF     (TSC_OFF + (size_t)BIMG * KPRE * 4)           // i32[8][2048]
#define TVLB_OFF    (TLB_OFF + (size_t)BIMG * KPRE * 4)           // u64[8][32]
#define WLIST_OFF   (TVLB_OFF + (size_t)BIMG * 32 * 8)            // u32[8][WLCAP]
#define CLIST_OFF   (WLIST_OFF + (size_t)BIMG * WLCAP * 4)        // u64[32000][NSLOT]
#define CVALID_OFF  (CLIST_OFF + (size_t)BIMG * NPROP * NSLOT * 8) // u64[32000][2]
#define MASK_OFF    (CVALID_OFF + (size_t)BIMG * NPROP * 2 * 8)   // u64[8][2048][32]
#define WS_NEED     (MASK_OFF + (size_t)BIMG * KPRE * 32 * 8)     // ~17.3 MB

__device__ __forceinline__ void decode_clip(const float4 rg, const float w, const float h,
                                            const float cx, const float cy,
                                            const float fw, const float fh, float bx[4]) {
    float dx = rg.x / 10.0f;
    float dy = rg.y / 10.0f;
    float dw = fminf(rg.z / 5.0f, BBOX_CLIP);
    float dh = fminf(rg.w / 5.0f, BBOX_CLIP);
    float pcx = dx * w + cx;
    float pcy = dy * h + cy;
    float pw  = expf(dw) * w;
    float phh = expf(dh) * h;
    bx[0] = fminf(fmaxf(pcx - 0.5f * pw,  0.0f), fw);
    bx[1] = fminf(fmaxf(pcy - 0.5f * phh, 0.0f), fh);
    bx[2] = fminf(fmaxf(pcx + 0.5f * pw,  0.0f), fw);
    bx[3] = fminf(fmaxf(pcy + 0.5f * phh, 0.0f), fh);
}

// K1: r13 verbatim (validated).
__global__ __launch_bounds__(256) void k1_score_hist(
    const float* __restrict__ logits, const float* __restrict__ reg,
    const float* __restrict__ props, const int* __restrict__ imh, const int* __restrict__ imw,
    u32* __restrict__ histrep, u64* __restrict__ clist, u64* __restrict__ cvalid) {
    const int lane = threadIdx.x & 63;
    const int pid = blockIdx.x * 4 + (threadIdx.x >> 6);
    if (pid >= BIMG * NPROP) return;
    const int img = pid / NPROP;
    const float fw = (float)imw[0], fh = (float)imh[0];
    const float* lrow = logits + (size_t)pid * NCLS;
    float v0 = lrow[lane];
    float v1 = (lane < 27) ? lrow[lane + 64] : -3.0e38f;
    float mx = fmaxf(v0, v1);
#pragma unroll
    for (int o = 32; o > 0; o >>= 1) mx = fmaxf(mx, __shfl_xor(mx, o));
    float es = expf(v0 - mx) + ((lane < 27) ? expf(v1 - mx) : 0.0f);
#pragma unroll
    for (int o = 32; o > 0; o >>= 1) es += __shfl_xor(es, o);
    const float thr = mx + logf(es) - 2.9967323f;   // ln(0.05) - 1e-3 margin
    float4 p = reinterpret_cast<const float4*>(props)[pid];
    const float w = p.z - p.x, h = p.w - p.y;
    const float cx = p.x + 0.5f * w, cy = p.y + 0.5f * h;
    const float4* rrow = reinterpret_cast<const float4*>(reg) + (size_t)pid * NCLS;
    const int n = pid - img * NPROP;
    const int rep = n & (NREP - 1);
    const float sh0 = __shfl(v0, (lane + 1) & 63);
    const float sh1 = __shfl(v1, (lane + 1) & 63);
    u64 w0 = 0ull, w1 = 0ull;
    u32 base1 = 0;
#pragma unroll
    for (int batch = 0; batch < 2; ++batch) {
        const int ci = lane + batch * 64;
        bool valid = false;
        u32 ob = 0u;
        if (ci < CM1) {
            const float l = (batch == 0) ? ((lane == 63) ? sh1 : sh0) : sh1;
            if (l > thr) {                        // rare (~2% of lanes)
                float sc = expf(l - mx) / es;     // exact
                float4 rg = rrow[ci + 1];
                float bx[4];
                decode_clip(rg, w, h, cx, cy, fw, fh, bx);
                valid = (sc > SCORE_T) && (bx[2] - bx[0] >= 1.0f) && (bx[3] - bx[1] >= 1.0f);
                if (valid) {
                    ob = __float_as_uint(sc) | 0x80000000u;  // sc > 0 always
                    atomicAdd(&histrep[((size_t)img * NREP + rep) * NBUCKET + (ob >> 20)], 1u);
                }
            }
        }
        const u64 bal = __ballot(valid);
        if (batch == 0) { w0 = bal; base1 = (u32)__popcll(bal); }
        else            { w1 = bal; }
        if (valid) {
            const u32 pre = (u32)__popcll(bal & ((1ull << lane) - 1ull));
            const u32 slot = (batch == 0) ? pre : (base1 + pre);   // <= 19 < NSLOT
            const u32 idx = (u32)n * CM1 + (u32)ci;
            clist[(size_t)pid * NSLOT + slot] = ((u64)ob << 32) | (u32)(~idx);
        }
    }
    if (lane == 0) {
        u64x2 v; v.x = w0; v.y = w1;
        reinterpret_cast<u64x2*>(cvalid)[pid] = v;
    }
}

// K2: register-accumulator uint4 scan (r16-phase-1 validated body as its own
// 8-block kernel; no 136KB LDS => no occupancy cliff). Integer-exact same
// outputs as the r13 LDS version.
__global__ __launch_bounds__(256) void k2_scan(
    const u32* __restrict__ histrep, u32* __restrict__ histtot,
    u32* __restrict__ start, u32* __restrict__ startrep, u32* __restrict__ meta,
    u32* __restrict__ wlist) {
    __shared__ u32 wsum[4], qws[4];
    __shared__ u32 TbkS, Vs;
    const int img = blockIdx.x;
    const int td = threadIdx.x;
    const int ln = td & 63, wv = td >> 6;
    const int lo = 4080 - td * 16;       // buckets [lo, lo+15]; bk(k) = lo+15-k
    u32 cnt[16];
#pragma unroll
    for (int k = 0; k < 16; ++k) cnt[k] = 0;
    const u32* hb = histrep + (size_t)img * NREP * NBUCKET + lo;
#pragma unroll
    for (int r = 0; r < NREP; ++r) {
        const uint4* q = reinterpret_cast<const uint4*>(hb + (size_t)r * NBUCKET);
        uint4 a = q[0], b = q[1], c = q[2], d = q[3];
        cnt[15] += a.x; cnt[14] += a.y; cnt[13] += a.z; cnt[12] += a.w;
        cnt[11] += b.x; cnt[10] += b.y; cnt[9]  += b.z; cnt[8]  += b.w;
        cnt[7]  += c.x; cnt[6]  += c.y; cnt[5]  += c.z; cnt[4]  += c.w;
        cnt[3]  += d.x; cnt[2]  += d.y; cnt[1]  += d.z; cnt[0]  += d.w;
    }
    u32 tsum = 0;
#pragma unroll
    for (int k = 0; k < 16; ++k) tsum += cnt[k];
    u32 inc = tsum;
#pragma unroll
    for (int o = 1; o < 64; o <<= 1) { u32 t = __shfl_up(inc, o); if (ln >= o) inc += t; }
    if (td == 0) TbkS = 0u;
    if (ln == 63) wsum[wv] = inc;
    __syncthreads();
    u32 wbase = 0;
    for (int i = 0; i < wv; ++i) wbase += wsum[i];
    if (td == 255) Vs = wbase + inc;
    const u32 excl0 = wbase + inc - tsum;
    u32 sub[16];
    u32 excl = excl0;
#pragma unroll
    for (int k = 0; k < 16; ++k) {
        const int bk = 4095 - (td * 16 + k);
        start[img * NBUCKET + bk] = excl;
        histtot[img * NBUCKET + bk] = cnt[k];
        sub[k] = excl;
        if (cnt[k] > 0 && excl < KPRE && excl + cnt[k] >= KPRE) TbkS = (u32)bk;  // <=1 writer
        excl += cnt[k];
    }
#pragma unroll
    for (int r = 0; r < NREP; ++r) {
        const uint4* q = reinterpret_cast<const uint4*>(hb + (size_t)r * NBUCKET);
        uint4 a = q[0], b = q[1], c = q[2], d = q[3];
        u32 hh[16] = { d.w, d.z, d.y, d.x, c.w, c.z, c.y, c.x,
                       b.w, b.z, b.y, b.x, a.w, a.z, a.y, a.x };
#pragma unroll
        for (int k = 0; k < 16; ++k) {
            const int bk = 4095 - (td * 16 + k);
            startrep[((size_t)img * NBUCKET + bk) * NREP + r] = sub[k];
            sub[k] += hh[k];
        }
    }
    u32 qcnt = 0;
    {
        u32 e = excl0;
#pragma unroll
        for (int k = 0; k < 16; ++k) { if (cnt[k] >= 2 && e < KPRE) ++qcnt; e += cnt[k]; }
    }
    u32 qinc = qcnt;
#pragma unroll
    for (int o = 1; o < 64; o <<= 1) { u32 t = __shfl_up(qinc, o); if (ln >= o) qinc += t; }
    if (ln == 63) qws[wv] = qinc;
    __syncthreads();
    u32 qbase = 0;
    for (int i = 0; i < wv; ++i) qbase += qws[i];
    u32 qoff = qbase + qinc - qcnt;
    {
        u32 e = excl0;
#pragma unroll
        for (int k = 0; k < 16; ++k) {
            const int bk = 4095 - (td * 16 + k);
            if (cnt[k] >= 2 && e < KPRE && qoff < WLCAP) wlist[img * WLCAP + (qoff++)] = (u32)bk;
            e += cnt[k];
        }
    }
    if (td == 255) meta[img * 8 + 3] = qbase + qinc;   // worklist count
    __syncthreads();
    if (td == 0) {
        u32 V = Vs;
        meta[img * 8 + 0] = V;
        meta[img * 8 + 1] = TbkS;
        meta[img * 8 + 2] = (V < KPRE) ? (KPRE - V) : 0u;
    }
}

// K3: r13 verbatim (4 threads/row).
__global__ __launch_bounds__(256) void k3_compact(
    const u64* __restrict__ clist, const u64* __restrict__ cvalid,
    const u32* __restrict__ startrep, const u32* __restrict__ meta,
    u32* __restrict__ bcntrep, u64* __restrict__ sel) {
    const u32 t = blockIdx.x * 256 + threadIdx.x;
    const u32 row = t >> 2;            // global pid
    const u32 s0 = t & 3;
    if (row < (u32)(BIMG * NPROP)) {
        const u64x2 vb = reinterpret_cast<const u64x2*>(cvalid)[row];
        const u32 rcnt = (u32)__popcll(vb.x) + (u32)__popcll(vb.y);
        if (s0 < rcnt) {
            const u32 img = row / NPROP;
            const u32 n = row - img * NPROP;
            const u32 rep = n & (NREP - 1);
            const u32 cutoff = meta[img * 8 + 1];
            for (u32 slot = s0; slot < rcnt; slot += 4) {
                const u64 e = clist[(size_t)row * NSLOT + slot];
                const u32 bk = (u32)(e >> 52);           // == (o >> 20)
                if (bk >= cutoff) {
                    const u32 pos = startrep[((size_t)img * NBUCKET + bk) * NREP + rep] +
                        atomicAdd(&bcntrep[((size_t)rep * BIMG + img) * NBUCKET + bk], 1u);
                    if (pos < SELCAP) sel[(size_t)img * SELCAP + pos] = e;
                }
            }
        }
    }
    // k3b rare path (need>0, never in practice): first `need` invalid idx ascending.
    if (blockIdx.x < BIMG && threadIdx.x < 64) {
        const int img = blockIdx.x;
        const u32 need = meta[img * 8 + 2];
        if (need != 0) {
            const u32 V = meta[img * 8 + 0];
            const int lv = threadIdx.x;
            const u32 ORDN1 = 0x407FFFFFu;  // ord_of(-1.0f)
            u32 filled = 0;
            for (u32 b0 = 0; b0 < MCAND && filled < need; b0 += 64) {
                const u32 idx = b0 + (u32)lv;
                bool inv = false;
                if (idx < MCAND) {
                    const u32 nn = (u32)(((u64)idx * 3054198967ull) >> 38);  // idx/90 exact
                    const u32 cq = idx - nn * 90u;
                    const u64 wb = cvalid[((size_t)img * NPROP + nn) * 2 + (cq >> 6)];
                    inv = ((wb >> (cq & 63)) & 1ull) == 0ull;
                }
                const u64 bal = __ballot(inv);
                const u32 pre = (u32)__popcll(bal & ((1ull << lv) - 1ull));
                if (inv && (filled + pre) < need)
                    sel[(size_t)img * SELCAP + V + filled + pre] =
                        ((u64)ORDN1 << 32) | (u32)(~idx);
                filled += (u32)__popcll(bal);
            }
        }
    }
}

// K4: r13 verbatim (LDS bitonic for cnt>64, wave shfl-bitonic for cnt<=64).
__global__ __launch_bounds__(256) void k4_sortseg(
    const u32* __restrict__ histtot, const u32* __restrict__ start,
    const u32* __restrict__ meta, const u32* __restrict__ wlist, u64* __restrict__ sel) {
    __shared__ u64 arr[4096];
    const int img = blockIdx.y;
    const int tid = threadIdx.x;
    const u32 wcount = meta[img * 8 + 3];
    // Phase A: big buckets
    for (u32 wi = blockIdx.x; wi < wcount; wi += gridDim.x) {
        const u32 bk = (wi < WLCAP) ? wlist[img * WLCAP + wi] : 0u;
        u32 cnt = histtot[img * NBUCKET + bk];
        u32 st = start[img * NBUCKET + bk];
        if (cnt <= 64 || st >= KPRE) continue;
        if (st + cnt > SELCAP) cnt = SELCAP - st;
        if (cnt > 4096) cnt = 4096;
        int n = 1;
        while (n < (int)cnt) n <<= 1;
        u64* seg = sel + (size_t)img * SELCAP + st;
        for (int i = tid; i < n; i += 256) arr[i] = (i < (int)cnt) ? seg[i] : 0ull;
        __syncthreads();
        for (int k = 2; k <= n; k <<= 1)
            for (int j = k >> 1; j > 0; j >>= 1) {
                for (int i = tid; i < n; i += 256) {
                    int ixj = i ^ j;
                    if (ixj > i) {
                        u64 a = arr[i], b = arr[ixj];
                        bool swp = ((i & k) == 0) ? (a < b) : (a > b);
                        if (swp) { arr[i] = b; arr[ixj] = a; }
                    }
                }
                __syncthreads();
            }
        for (int i = tid; i < (int)cnt; i += 256) seg[i] = arr[i];
        __syncthreads();
    }
    // Phase B: small buckets, one wave each
    const int wv = tid >> 6, lane = tid & 63;
    for (u32 wi = blockIdx.x * 4 + wv; wi < wcount; wi += gridDim.x * 4) {
        const u32 bk = (wi < WLCAP) ? wlist[img * WLCAP + wi] : 0u;
        u32 cnt = histtot[img * NBUCKET + bk];
        u32 st = start[img * NBUCKET + bk];
        if (cnt < 2 || cnt > 64 || st >= KPRE) continue;
        if (st + cnt > SELCAP) cnt = SELCAP - st;
        u64* seg = sel + (size_t)img * SELCAP + st;
        u64 key = (lane < (int)cnt) ? seg[lane] : 0ull;   // 0 sinks (real keys have MSB set)
#pragma unroll
        for (int k = 2; k <= 64; k <<= 1) {
#pragma unroll
            for (int j = k >> 1; j > 0; j >>= 1) {
                u64 other = __shfl_xor(key, j);
                bool takeMax = ((lane & j) == 0) == ((lane & k) == 0);
                u64 hi2 = (key > other) ? key : other;
                u64 lo2 = (key > other) ? other : key;
                key = takeMax ? hi2 : lo2;
            }
        }
        if (lane < (int)cnt) seg[lane] = key;
    }
}

// K5: r13 verbatim (1024 threads per image).
__global__ __launch_bounds__(1024) void k5_gather(
    const u64* __restrict__ sel, const float* __restrict__ reg, const float* __restrict__ props,
    const int* __restrict__ imh, const int* __restrict__ imw,
    float* __restrict__ tbox, float* __restrict__ tsb, float* __restrict__ tsc,
    int* __restrict__ tlb, u64* __restrict__ tvlb) {
    const int img = blockIdx.x;
    const int tid = threadIdx.x;
    const float fw = (float)imw[0], fh = (float)imh[0];
    float bx[2][4];
    int lab[2];
    float lm = -3.0e38f;
#pragma unroll
    for (int t = 0; t < 2; ++t) {
        int s = t * 1024 + tid;
        u64 key = sel[(size_t)img * SELCAP + s];
        u32 o = (u32)(key >> 32);
        u32 idx = ~((u32)key);
        u32 b = (o & 0x80000000u) ? (o & 0x7FFFFFFFu) : ~o;
        float sc = __uint_as_float(b);               // exact masked score roundtrip
        u32 n = idx / CM1;
        int c = (int)(idx - n * CM1) + 1;
        int pid = img * NPROP + (int)n;
        float4 p = reinterpret_cast<const float4*>(props)[pid];
        float w = p.z - p.x, h = p.w - p.y;
        float cx = p.x + 0.5f * w, cy = p.y + 0.5f * h;
        float4 rg = reinterpret_cast<const float4*>(reg)[(size_t)pid * NCLS + c];
        decode_clip(rg, w, h, cx, cy, fw, fh, bx[t]);
        lab[t] = c;
        lm = fmaxf(lm, fmaxf(fmaxf(bx[t][0], bx[t][1]), fmaxf(bx[t][2], bx[t][3])));
        reinterpret_cast<float4*>(tbox)[(size_t)img * KPRE + s] =
            make_float4(bx[t][0], bx[t][1], bx[t][2], bx[t][3]);
        tsc[(size_t)img * KPRE + s] = sc;
        tlb[(size_t)img * KPRE + s] = c;
        u64 bw = __ballot(sc > SCORE_T);             // word = s>>6 = t*16 + wave
        if ((tid & 63) == 0) tvlb[img * 32 + t * 16 + (tid >> 6)] = bw;
    }
#pragma unroll
    for (int o2 = 32; o2 > 0; o2 >>= 1) lm = fmaxf(lm, __shfl_xor(lm, o2));
    __shared__ float wm[16];
    if ((tid & 63) == 0) wm[tid >> 6] = lm;
    __syncthreads();
    float m = wm[0];
#pragma unroll
    for (int i = 1; i < 16; ++i) m = fmaxf(m, wm[i]);
    const float mplus = m + 1.0f;
#pragma unroll
    for (int t = 0; t < 2; ++t) {
        int s = t * 1024 + tid;
        float off = (float)lab[t] * mplus;
        reinterpret_cast<float4*>(tsb)[(size_t)img * KPRE + s] =
            make_float4(bx[t][0] + off, bx[t][1] + off, bx[t][2] + off, bx[t][3] + off);
    }
}

// K6: r16-validated body (4 upper-triangular tiles per 256-thr block).
__global__ __launch_bounds__(256) void k6_mask(
    const float* __restrict__ tsb, u64* __restrict__ mask) {
    const int img = blockIdx.y;
    const int wv = threadIdx.x >> 6, lane = threadIdx.x & 63;
    const u32 t = blockIdx.x * 4 + wv;             // < 528 (132*4)
    float f = sqrtf(8.0f * (float)t + 1.0f);
    u32 x = (u32)((f - 1.0f) * 0.5f);
    while ((x + 1) * (x + 2) / 2 <= t) ++x;
    while (x * (x + 1) / 2 > t) --x;
    const u32 y = t - x * (x + 1) / 2;             // x >= y guaranteed
    const int j0 = (int)x * 64;                    // column block
    const int i0 = (int)y * 64;                    // row block
    __shared__ float4 cb[4][64];
    __shared__ float ca[4][64];
    float4 c = reinterpret_cast<const float4*>(tsb)[(size_t)img * KPRE + j0 + lane];
    cb[wv][lane] = c;
    ca[wv][lane] = (c.z - c.x) * (c.w - c.y);
    __syncthreads();
    const int i = i0 + lane;
    float4 r = reinterpret_cast<const float4*>(tsb)[(size_t)img * KPRE + i];
    float ra = (r.z - r.x) * (r.w - r.y);
    u64 bits = 0ull;
#pragma unroll 8
    for (int jj = 0; jj < 64; ++jj) {
        int j = j0 + jj;
        float4 cc = cb[wv][jj];
        float wvv = fmaxf(fminf(r.z, cc.z) - fmaxf(r.x, cc.x), 0.0f);
        float hvv = fmaxf(fminf(r.w, cc.w) - fmaxf(r.y, cc.y), 0.0f);
        float inter = wvv * hvv;
        float iou = inter / ((ra + ca[wv][jj]) - inter);   // NaN compares false
        if ((iou > NMS_T) && (j > i)) bits |= (1ull << jj);
    }
    mask[((size_t)img * KPRE + i) * 32 + (j0 >> 6)] = bits;
}

// K7+K8 fused greedy NMS + select (r13 verbatim, sub-diagonal gates).
__device__ __forceinline__ u64 rdlane64(u64 v, int l) {
    u32 lo = (u32)__builtin_amdgcn_readlane((int)(u32)v, l);
    u32 hi = (u32)__builtin_amdgcn_readlane((int)(u32)(v >> 32), l);
    return ((u64)hi << 32) | lo;
}

__device__ __forceinline__ void g2l16(const void* g, void* l) {
    __builtin_amdgcn_global_load_lds(
        (const __attribute__((address_space(1))) void*)g,
        (__attribute__((address_space(3))) void*)l, 16, 0, 0);
}

__global__ __launch_bounds__(64) void k7_nms_sel(
    const u64* __restrict__ mask, const u64* __restrict__ tvlb,
    const float* __restrict__ tsc, const float* __restrict__ tbox,
    const int* __restrict__ tlb, float* __restrict__ out) {
    __shared__ u64 smem[4096];           // 2 x 16 KB double buffer
    const int img = blockIdx.x;
    const int lane = threadIdx.x;
    const int lg = lane >> 4;
    const int wlo = 2 * (lane & 15);
    const u64* mrow = mask + (size_t)img * KPRE * 32;

    u64 accx, accy, rp;
    {
        u64 nv = 0ull;
        if (lane < 32) nv = ~tvlb[img * 32 + lane];   // invalid word `lane`
        rp   = __shfl(nv, 0);
        accx = __shfl(nv, (lane & 15) * 2);
        accy = __shfl(nv, (lane & 15) * 2 + 1);
    }

    {
        const char* gsrc = (const char*)mrow + (size_t)lane * 16;
#pragma unroll
        for (int t = 0; t < 16; ++t)
            g2l16(gsrc + (size_t)t * 1024, (char*)smem + (size_t)t * 1024);
    }
    u64 diag = mrow[(size_t)lane * 32];

    u32 tk = 0;
    int bcut = 31;

#pragma unroll 1
    for (int b = 0; b < 32; ++b) {
        const size_t base32 = (size_t)b * 2048;
        const u64* cbuf = smem + (size_t)(b & 1) * 2048;

        u64 diagn = 0ull;
        if (b + 1 < 32) {
            diagn = mrow[base32 + 2048 + (size_t)lane * 32 + (b + 1)];
            const char* gsrc = (const char*)(mrow + base32 + 2048) + (size_t)lane * 16;
            char* nb_l = (char*)(smem + (size_t)((b + 1) & 1) * 2048);
#pragma unroll
            for (int t = 0; t < 16; ++t)
                g2l16(gsrc + (size_t)t * 1024, nb_l + (size_t)t * 1024);
        }

        u64 A = rp;
#pragma unroll
        for (int u = 0; u < 64; ++u) {
            u64 row = rdlane64(diag, u);
            if (!((A >> u) & 1ull)) A |= row;
        }
        const u64 keptw = ~A;

        if (b + 1 < 32) asm volatile("s_waitcnt vmcnt(17)" ::: "memory");
        else            asm volatile("s_waitcnt vmcnt(0)" ::: "memory");

        const u64 gx = (wlo >= b) ? ~0ull : 0ull;       // sub-diagonal word gate
        const u64 gy = (wlo + 1 >= b) ? ~0ull : 0ull;

#define LDV(K) u64x2 v##K = *(const u64x2*)&cbuf[128 * (K) + 2 * lane];
#define PRV(K) { u32 nib = (u32)(keptw >> (4 * (K))) & 15u; \
                 u32 kb = (nib >> lg) & 1u; \
                 accx |= kb ? (v##K.x & gx) : 0ull; accy |= kb ? (v##K.y & gy) : 0ull; }
        LDV(0) LDV(1) LDV(2) LDV(3)
        LDV(4) LDV(5) LDV(6) LDV(7)     PRV(0) PRV(1) PRV(2) PRV(3)
        LDV(8) LDV(9) LDV(10) LDV(11)   PRV(4) PRV(5) PRV(6) PRV(7)
        LDV(12) LDV(13) LDV(14) LDV(15) PRV(8) PRV(9) PRV(10) PRV(11)
        PRV(12) PRV(13) PRV(14) PRV(15)
#undef LDV
#undef PRV

        tk += (u32)__popcll(keptw);
        if (tk >= (u32)DETS) { bcut = b; break; }

        const int nb2 = b + 1;
        if (nb2 < 32) {
            u64 asel = (nb2 & 1) ? accy : accx;
            const int sl = (nb2 >> 1) & 15;
            rp = rdlane64(asel, sl) | rdlane64(asel, sl + 16) |
                 rdlane64(asel, sl + 32) | rdlane64(asel, sl + 48);
        }
        diag = diagn;
    }

    asm volatile("s_waitcnt vmcnt(0)" ::: "memory");   // drain in-flight DMA

    accx |= __shfl_xor(accx, 16); accx |= __shfl_xor(accx, 32);
    accy |= __shfl_xor(accy, 16); accy |= __shfl_xor(accy, 32);

    u64 mxv = __shfl(accx, (lane >> 1) & 15);
    u64 myv = __shfl(accy, (lane >> 1) & 15);
    u64 kw = (lane & 1) ? ~myv : ~mxv;
    if (lane >= 32 || lane > bcut) kw = 0ull;

    u32 cnt = (u32)__popcll(kw);
    u32 inc = cnt;
#pragma unroll
    for (int o = 1; o < 64; o <<= 1) { u32 t = __shfl_up(inc, o); if (lane >= o) inc += t; }
    const u32 excl = inc - cnt;
    const u32 total = (u32)__shfl(inc, 63);

    float* ob0 = out + (size_t)img * DETS * 4;
    float* os0 = out + (size_t)BIMG * DETS * 4 + (size_t)img * DETS;
    float* ol0 = out + (size_t)BIMG * DETS * 5 + (size_t)img * DETS;

#pragma unroll
    for (int t = 0; t < 2; ++t) {
        u32 r = (u32)lane + (u32)t * 64;
        if (r < DETS && r >= total) {
            reinterpret_cast<float4*>(ob0)[r] = make_float4(0.f, 0.f, 0.f, 0.f);
            os0[r] = 0.0f;
            ol0[r] = -1.0f;
        }
    }
    u64 w = kw;
    u32 r = excl;
    while (w != 0ull && r < DETS) {
        int p = __ffsll((unsigned long long)w) - 1;
        w &= (w - 1ull);
        u32 s = (u32)lane * 64u + (u32)p;
        reinterpret_cast<float4*>(ob0)[r] =
            reinterpret_cast<const float4*>(tbox)[(size_t)img * KPRE + s];
        os0[r] = tsc[(size_t)img * KPRE + s];
        ol0[r] = (float)tlb[(size_t)img * KPRE + s];
        ++r;
    }
}

extern "C" void kernel_launch(void* const* d_in, const int* in_sizes, int n_in,
                              void* d_out, int out_size, void* d_ws, size_t ws_size,
                              hipStream_t stream) {
    const float* logits = (const float*)d_in[0];
    const float* reg    = (const float*)d_in[1];
    const float* props  = (const float*)d_in[2];
    const int*   imh    = (const int*)d_in[3];
    const int*   imw    = (const int*)d_in[4];
    float* out = (float*)d_out;
    char* ws = (char*)d_ws;
    if (ws_size < WS_NEED) return;  // ~17.3 MB needed

    u32* histrep  = (u32*)(ws + HISTREP_OFF);
    u32* bcntrep  = (u32*)(ws + BCNTREP_OFF);
    u32* meta     = (u32*)(ws + META_OFF);
    u32* start    = (u32*)(ws + START_OFF);
    u32* histtot  = (u32*)(ws + HISTTOT_OFF);
    u32* startrep = (u32*)(ws + STARTREP_OFF);
    u64* sel  = (u64*)(ws + SEL_OFF);
    float* tbox = (float*)(ws + TBOX_OFF);
    float* tsb  = (float*)(ws + TSB_OFF);
    float* tsc  = (float*)(ws + TSC_OFF);
    int*   tlb  = (int*)(ws + TLB_OFF);
    u64*   tvlb = (u64*)(ws + TVLB_OFF);
    u32*   wlist = (u32*)(ws + WLIST_OFF);
    u64*   clist = (u64*)(ws + CLIST_OFF);
    u64*   cvalid = (u64*)(ws + CVALID_OFF);
    u64*   mask = (u64*)(ws + MASK_OFF);

    hipMemsetAsync(d_ws, 0, ZERO_BYTES, stream);  // histrep, bcntrep, meta

    k1_score_hist<<<BIMG * NPROP / 4, 256, 0, stream>>>(logits, reg, props, imh, imw,
                                                        histrep, clist, cvalid);
    k2_scan<<<BIMG, 256, 0, stream>>>(histrep, histtot, start, startrep, meta, wlist);
    k3_compact<<<(BIMG * NPROP * 4) / 256, 256, 0, stream>>>(clist, cvalid, startrep,
                                                             meta, bcntrep, sel);
    k4_sortseg<<<dim3(64, BIMG), 256, 0, stream>>>(histtot, start, meta, wlist, sel);
    k5_gather<<<BIMG, 1024, 0, stream>>>(sel, reg, props, imh, imw, tbox, tsb, tsc, tlb, tvlb);
    k6_mask<<<dim3(132, BIMG), 256, 0, stream>>>(tsb, mask);
    k7_nms_sel<<<BIMG, 64, 0, stream>>>(mask, tvlb, tsc, tbox, tlb, out);
}